// Round 14
// baseline (116.990 us; speedup 1.0000x reference)
//
#include <hip/hip_runtime.h>
#include <math.h>

#define NN 8192
#define CC 256
#define LOG2N 13

typedef float f32x4 __attribute__((ext_vector_type(4)));

// ---------------- ws layout (floats) ----------------
// aggP : [256][256]  offset 0      (agg partials per 32-row chunk; slot-written, no memset)
// mvP  : [20][256]   offset 65536  (m*4+q; m: 0=Wxz->Z 1=Whz->Z 2=Wxr->R 3=Whr->R 4=Wxh->XH)
#define WS_AGGP 0
#define WS_MVP  65536

#define NAGG 256
#define NMV  20

// A: serial prefix — ONLY the 8.4 MB H read + 1.25 MB weights; no bulk writes.
// 256 agg blocks (32 rows each) for 2x the in-flight H loads vs 128 blocks.
__global__ void __launch_bounds__(256) kA(
        const float* __restrict__ X, const float* __restrict__ E,
        const float* __restrict__ H,
        const int* __restrict__ dh, const int* __restrict__ dt,
        const float* __restrict__ Wxz, const float* __restrict__ Whz,
        const float* __restrict__ Wxr, const float* __restrict__ Whr,
        const float* __restrict__ Wxh,
        float* __restrict__ ws) {
    const int bid = blockIdx.x;
    const int t = threadIdx.x;
    const int head = dh[0], tail = dt[0];
    float* aggP = ws + WS_AGGP;
    float* mvP  = ws + WS_MVP;

    if (bid < NAGG) {
        __shared__ float e_sh[32];
        __shared__ f32x4 red[4][64];
        const int i0 = bid * 32;
        if (t < 32) {
            const int i = i0 + t;
            float e = 0.5f * E[(size_t)head * NN + i];
            if (head != tail) e += 0.5f * E[(size_t)tail * NN + i];
            if (i == tail) e += 0.5f;
            e_sh[t] = e;
        }
        __syncthreads();
        const int g = t >> 6, c = (t & 63) << 2;
        f32x4 acc = {0.f, 0.f, 0.f, 0.f};
        #pragma unroll
        for (int it = 0; it < 8; ++it) {
            const int r = it * 4 + g;
            const f32x4 hv = *(const f32x4*)(H + (size_t)(i0 + r) * CC + c);
            acc += hv * e_sh[r];
        }
        red[g][t & 63] = acc;
        __syncthreads();
        if (g == 0) {
            const f32x4 s = red[0][t] + red[1][t] + red[2][t] + red[3][t];
            *(f32x4*)(aggP + bid * CC + (t << 2)) = s;
        }
        return;
    }

    // mv role
    {
        const int mb = bid - NAGG;
        const int m = mb >> 2, q = mb & 3;
        __shared__ float v_sh[64];
        const float* W;
        switch (m) {
            case 0: W = Wxz; break; case 1: W = Whz; break;
            case 2: W = Wxr; break; case 3: W = Whr; break;
            default: W = Wxh; break;
        }
        if (t < 64) {
            const int k = q * 64 + t;
            v_sh[t] = (m == 1 || m == 3) ? H[(size_t)head * CC + k] : X[k];
        }
        __syncthreads();
        float acc = 0.f;
        #pragma unroll
        for (int kk = 0; kk < 64; ++kk)
            acc += v_sh[kk] * W[(size_t)(q * 64 + kk) * CC + t];
        mvP[mb * CC + t] = acc;
    }
}

// B: grid = 2048 (exact residency). Block 0 = epilogue: GRU head row of H_new AND
// the full head row of E_new (streamers skip it — no gather in the hot loop).
// Blocks 1..2047 stream E_new + H copy: grid-sweep, 2-deep nt loads, plain stores.
__global__ void __launch_bounds__(256) kB(
        const float* __restrict__ E, const float* __restrict__ H,
        const int* __restrict__ dh, const int* __restrict__ dt,
        const float* __restrict__ Cz, const float* __restrict__ Cr,
        const float* __restrict__ Whh,
        const float* __restrict__ bz, const float* __restrict__ br,
        const float* __restrict__ bh,
        const float* __restrict__ ws, float* __restrict__ out) {
    const int head = dh[0], tail = dt[0];
    const size_t nn = (size_t)NN * NN;
    const float* aggP = ws + WS_AGGP;
    const float* mvP  = ws + WS_MVP;

    if (blockIdx.x == 0) {
        const int t = threadIdx.x;
        // ---- E_new head row (streamers skip it; race-free) ----
        #pragma unroll
        for (int it = 0; it < 8; ++it) {
            const int j = (it * 256 + t) << 2;
            const f32x4 v = *(const f32x4*)(E + (size_t)head * NN + j);
            f32x4 o = v * 0.5f;
            if (head != tail) {
                const f32x4 w = *(const f32x4*)(E + (size_t)tail * NN + j);
                o += w * 0.5f;
            }
            if (tail >= j && tail < j + 4) o[tail - j] += 0.5f;
            *(f32x4*)(out + (size_t)head * NN + j) = o;
        }
        // ---- GRU epilogue ----
        __shared__ float agg_sh[CC];
        __shared__ float rs_sh[CC];
        float a = 0.f;
        #pragma unroll 8
        for (int b = 0; b < NAGG; ++b) a += aggP[b * CC + t];
        agg_sh[t] = a;
        __syncthreads();
        float pz = 0.f, pr = 0.f;
        #pragma unroll 8
        for (int k = 0; k < CC; ++k) {
            const float av = agg_sh[k];
            pz += av * Cz[(size_t)k * CC + t];
            pr += av * Cr[(size_t)k * CC + t];
        }
        float sz = bz[t] + pz, sr = br[t] + pr, sxh = 0.f;
        #pragma unroll
        for (int p = 0; p < 8; ++p)   sz += mvP[p * CC + t];
        #pragma unroll
        for (int p = 8; p < 16; ++p)  sr += mvP[p * CC + t];
        #pragma unroll
        for (int p = 16; p < 20; ++p) sxh += mvP[p * CC + t];
        const float h = H[(size_t)head * CC + t];
        const float r = 1.f / (1.f + expf(-sr));
        rs_sh[t] = h * r;
        __syncthreads();
        float hh = 0.f;
        #pragma unroll 16
        for (int k = 0; k < CC; ++k)
            hh += rs_sh[k] * Whh[(size_t)k * CC + t];
        const float z = 1.f / (1.f + expf(-sz));
        const float ht = tanhf(bh[t] + sxh + hh);
        out[nn + (size_t)head * CC + t] = z * h + (1.f - z) * ht;
        return;
    }

    // streamers: blocks 1..2047 over E region + H region (head rows skipped)
    const size_t total4 = (nn + (size_t)NN * CC) >> 2;   // 17,301,504
    const size_t step = (size_t)2047 * 256;              // 524,032

    auto load_elem = [&](size_t idx) -> f32x4 {
        const size_t e = idx << 2;
        if (e < nn) return __builtin_nontemporal_load((const f32x4*)(E + e));
        return __builtin_nontemporal_load((const f32x4*)(H + (e - nn)));
    };
    auto compute_store = [&](size_t idx, f32x4 v) {
        const size_t e = idx << 2;
        if (e < nn) {
            if ((int)(e >> LOG2N) != head) {
                const f32x4 o = v * 0.5f;
                *(f32x4*)(out + e) = o;
            }
        } else {
            const size_t tt = e - nn;
            if ((int)(tt >> 8) != head)
                *(f32x4*)(out + nn + tt) = v;
        }
    };

    for (size_t idx = (size_t)(blockIdx.x - 1) * 256 + threadIdx.x;
         idx < total4; idx += 2 * step) {
        const size_t idx2 = idx + step;
        const bool ok2 = idx2 < total4;
        const f32x4 a = load_elem(idx);
        f32x4 b = {0.f, 0.f, 0.f, 0.f};
        if (ok2) b = load_elem(idx2);
        compute_store(idx, a);
        if (ok2) compute_store(idx2, b);
    }
}

extern "C" void kernel_launch(void* const* d_in, const int* in_sizes, int n_in,
                              void* d_out, int out_size, void* d_ws, size_t ws_size,
                              hipStream_t stream) {
    const float* X    = (const float*)d_in[0];
    const int*   dh   = (const int*)d_in[1];
    const int*   dt   = (const int*)d_in[2];
    const float* E    = (const float*)d_in[3];
    const float* H    = (const float*)d_in[4];
    const float* Wxz  = (const float*)d_in[5];
    const float* Whz  = (const float*)d_in[6];
    const float* Cz   = (const float*)d_in[7];
    const float* bz   = (const float*)d_in[8];
    const float* Wxr  = (const float*)d_in[9];
    const float* Whr  = (const float*)d_in[10];
    const float* Cr   = (const float*)d_in[11];
    const float* br   = (const float*)d_in[12];
    const float* Wxh  = (const float*)d_in[13];
    const float* Whh  = (const float*)d_in[14];
    const float* bh   = (const float*)d_in[15];
    float* out = (float*)d_out;
    float* ws  = (float*)d_ws;

    kA<<<NAGG + NMV, 256, 0, stream>>>(X, E, H, dh, dt, Wxz, Whz, Wxr, Whr, Wxh, ws);
    kB<<<2048, 256, 0, stream>>>(E, H, dh, dt, Cz, Cr, Whh, bz, br, bh, ws, out);
}

// Round 15
// 101.976 us; speedup vs baseline: 1.1472x; 1.1472x over previous
//
#include <hip/hip_runtime.h>
#include <math.h>

#define NN 8192
#define CC 256
#define LOG2N 13

typedef float f32x4 __attribute__((ext_vector_type(4)));

// ---------------- ws layout (floats) ----------------
// aggP : [128][256]  offset 0      (agg partials per 64-row chunk; slot-written, no memset)
// mvP  : [20][256]   offset 32768  (m*4+q; m: 0=Wxz->Z 1=Whz->Z 2=Wxr->R 3=Whr->R 4=Wxh->XH)
#define WS_AGGP 0
#define WS_MVP  32768

#define NAGG 128
#define NMV  20

// A: serial prefix — ONLY the 8.4 MB H read + 1.25 MB weights; no bulk writes.
__global__ void __launch_bounds__(256) kA(
        const float* __restrict__ X, const float* __restrict__ E,
        const float* __restrict__ H,
        const int* __restrict__ dh, const int* __restrict__ dt,
        const float* __restrict__ Wxz, const float* __restrict__ Whz,
        const float* __restrict__ Wxr, const float* __restrict__ Whr,
        const float* __restrict__ Wxh,
        float* __restrict__ ws) {
    const int bid = blockIdx.x;
    const int t = threadIdx.x;
    const int head = dh[0], tail = dt[0];
    float* aggP = ws + WS_AGGP;
    float* mvP  = ws + WS_MVP;

    if (bid < NAGG) {
        __shared__ float e_sh[64];
        __shared__ f32x4 red[4][64];
        const int i0 = bid * 64;
        if (t < 64) {
            const int i = i0 + t;
            float e = 0.5f * E[(size_t)head * NN + i];
            if (head != tail) e += 0.5f * E[(size_t)tail * NN + i];
            if (i == tail) e += 0.5f;
            e_sh[t] = e;
        }
        __syncthreads();
        const int g = t >> 6, c = (t & 63) << 2;
        f32x4 acc = {0.f, 0.f, 0.f, 0.f};
        #pragma unroll
        for (int it = 0; it < 16; ++it) {
            const int r = it * 4 + g;
            const f32x4 hv = *(const f32x4*)(H + (size_t)(i0 + r) * CC + c);
            acc += hv * e_sh[r];
        }
        red[g][t & 63] = acc;
        __syncthreads();
        if (g == 0) {
            const f32x4 s = red[0][t] + red[1][t] + red[2][t] + red[3][t];
            *(f32x4*)(aggP + bid * CC + (t << 2)) = s;
        }
        return;
    }

    // mv role
    {
        const int mb = bid - NAGG;
        const int m = mb >> 2, q = mb & 3;
        __shared__ float v_sh[64];
        const float* W;
        switch (m) {
            case 0: W = Wxz; break; case 1: W = Whz; break;
            case 2: W = Wxr; break; case 3: W = Whr; break;
            default: W = Wxh; break;
        }
        if (t < 64) {
            const int k = q * 64 + t;
            v_sh[t] = (m == 1 || m == 3) ? H[(size_t)head * CC + k] : X[k];
        }
        __syncthreads();
        float acc = 0.f;
        #pragma unroll
        for (int kk = 0; kk < 64; ++kk)
            acc += v_sh[kk] * W[(size_t)(q * 64 + kk) * CC + t];
        mvP[mb * CC + t] = acc;
    }
}

// B: grid = 2048 (exact residency: 256 CU x 8 blocks of 256 thr). Block 0 = full GRU
// epilogue (hidden under stream). Blocks 1..2047 stream E_new + H copy: grid-sweep,
// 2-deep nt-load clustering, plain stores, in-loop head fixup (R13-proven).
__global__ void __launch_bounds__(256) kB(
        const float* __restrict__ E, const float* __restrict__ H,
        const int* __restrict__ dh, const int* __restrict__ dt,
        const float* __restrict__ Cz, const float* __restrict__ Cr,
        const float* __restrict__ Whh,
        const float* __restrict__ bz, const float* __restrict__ br,
        const float* __restrict__ bh,
        const float* __restrict__ ws, float* __restrict__ out) {
    const int head = dh[0], tail = dt[0];
    const size_t nn = (size_t)NN * NN;
    const float* aggP = ws + WS_AGGP;
    const float* mvP  = ws + WS_MVP;

    if (blockIdx.x == 0) {
        __shared__ float agg_sh[CC];
        __shared__ float rs_sh[CC];
        const int t = threadIdx.x;
        float a = 0.f;
        #pragma unroll 8
        for (int b = 0; b < NAGG; ++b) a += aggP[b * CC + t];
        agg_sh[t] = a;
        __syncthreads();
        float pz = 0.f, pr = 0.f;
        #pragma unroll 8
        for (int k = 0; k < CC; ++k) {
            const float av = agg_sh[k];
            pz += av * Cz[(size_t)k * CC + t];
            pr += av * Cr[(size_t)k * CC + t];
        }
        float sz = bz[t] + pz, sr = br[t] + pr, sxh = 0.f;
        #pragma unroll
        for (int p = 0; p < 8; ++p)   sz += mvP[p * CC + t];
        #pragma unroll
        for (int p = 8; p < 16; ++p)  sr += mvP[p * CC + t];
        #pragma unroll
        for (int p = 16; p < 20; ++p) sxh += mvP[p * CC + t];
        const float h = H[(size_t)head * CC + t];
        const float r = 1.f / (1.f + expf(-sr));
        rs_sh[t] = h * r;
        __syncthreads();
        float hh = 0.f;
        #pragma unroll 16
        for (int k = 0; k < CC; ++k)
            hh += rs_sh[k] * Whh[(size_t)k * CC + t];
        const float z = 1.f / (1.f + expf(-sz));
        const float ht = tanhf(bh[t] + sxh + hh);
        out[nn + (size_t)head * CC + t] = z * h + (1.f - z) * ht;
        return;
    }

    // streamers: blocks 1..2047 over E region + H region
    const size_t total4 = (nn + (size_t)NN * CC) >> 2;   // 17,301,504
    const size_t step = (size_t)2047 * 256;              // 524,032

    auto load_elem = [&](size_t idx) -> f32x4 {
        const size_t e = idx << 2;
        if (e < nn) return __builtin_nontemporal_load((const f32x4*)(E + e));
        return __builtin_nontemporal_load((const f32x4*)(H + (e - nn)));
    };
    auto compute_store = [&](size_t idx, f32x4 v) {
        const size_t e = idx << 2;
        if (e < nn) {
            f32x4 o = v * 0.5f;
            if ((int)(e >> LOG2N) == head) {
                const int j = (int)(e & (NN - 1));
                if (head != tail) {
                    const f32x4 w = *(const f32x4*)(E + (size_t)tail * NN + j);
                    o += w * 0.5f;
                }
                if (tail >= j && tail < j + 4) o[tail - j] += 0.5f;
            }
            *(f32x4*)(out + e) = o;
        } else {
            const size_t tt = e - nn;
            if ((int)(tt >> 8) != head)
                *(f32x4*)(out + nn + tt) = v;
        }
    };

    for (size_t idx = (size_t)(blockIdx.x - 1) * 256 + threadIdx.x;
         idx < total4; idx += 2 * step) {
        const size_t idx2 = idx + step;
        const bool ok2 = idx2 < total4;
        const f32x4 a = load_elem(idx);
        f32x4 b = {0.f, 0.f, 0.f, 0.f};
        if (ok2) b = load_elem(idx2);
        compute_store(idx, a);
        if (ok2) compute_store(idx2, b);
    }
}

extern "C" void kernel_launch(void* const* d_in, const int* in_sizes, int n_in,
                              void* d_out, int out_size, void* d_ws, size_t ws_size,
                              hipStream_t stream) {
    const float* X    = (const float*)d_in[0];
    const int*   dh   = (const int*)d_in[1];
    const int*   dt   = (const int*)d_in[2];
    const float* E    = (const float*)d_in[3];
    const float* H    = (const float*)d_in[4];
    const float* Wxz  = (const float*)d_in[5];
    const float* Whz  = (const float*)d_in[6];
    const float* Cz   = (const float*)d_in[7];
    const float* bz   = (const float*)d_in[8];
    const float* Wxr  = (const float*)d_in[9];
    const float* Whr  = (const float*)d_in[10];
    const float* Cr   = (const float*)d_in[11];
    const float* br   = (const float*)d_in[12];
    const float* Wxh  = (const float*)d_in[13];
    const float* Whh  = (const float*)d_in[14];
    const float* bh   = (const float*)d_in[15];
    float* out = (float*)d_out;
    float* ws  = (float*)d_ws;

    kA<<<NAGG + NMV, 256, 0, stream>>>(X, E, H, dh, dt, Wxz, Whz, Wxr, Whr, Wxh, ws);
    kB<<<2048, 256, 0, stream>>>(E, H, dh, dt, Cz, Cr, Whh, bz, br, bh, ws, out);
}